// Round 1
// baseline (5666.290 us; speedup 1.0000x reference)
//
#include <hip/hip_runtime.h>
#include <math.h>

#define NR 8192      // NA == NT
#define DIM 256
#define NCH 64       // column-pass row chunks
#define CHR 128      // rows per chunk (NR / NCH)

// ---------------- online LSE helpers ----------------
__device__ __forceinline__ void lse_upd(float& m, float& s, float v) {
    float mn = fmaxf(m, v);
    float e  = __expf(fminf(m, v) - mn);   // exp(-|v-m|); handles m=-inf (e=0)
    s = (v > m) ? fmaf(s, e, 1.0f) : (s + e);
    m = mn;
}

__device__ __forceinline__ void lse_comb(float& m, float& s, float mo, float so) {
    float mn = fmaxf(m, mo);
    s = s * __expf(m - mn) + so * __expf(mo - mn);
    m = mn;
}

// ---------------- init ----------------
__global__ void init_zero(float* __restrict__ g, float* __restrict__ sum) {
    int t = blockIdx.x * 256 + threadIdx.x;
    if (t < NR) g[t] = 0.0f;
    if (t == 0) *sum = 0.0f;
}

// ---------------- out[M,DIM] = A[M,DIM] @ W[DIM,DIM] + bias ----------------
// BM=BN=64, BK=16, 256 threads, 4x4 micro-tile
__global__ __launch_bounds__(256) void gemm_qk(const float* __restrict__ A,
                                               const float* __restrict__ W,
                                               const float* __restrict__ bias,
                                               float* __restrict__ out) {
    __shared__ float As[16][68];
    __shared__ float Ws[16][68];
    const int t  = threadIdx.x;
    const int r0 = blockIdx.x * 64;
    const int c0 = blockIdx.y * 64;
    const int ty = t >> 4, tx = t & 15;
    const int arow = t >> 2;        // 0..63
    const int ak   = (t & 3) * 4;   // 0,4,8,12
    const int wrow = t >> 4;        // 0..15
    const int wcol = (t & 15) * 4;  // 0..60
    float acc[4][4] = {};
    for (int k0 = 0; k0 < DIM; k0 += 16) {
        float4 av = *(const float4*)(A + (size_t)(r0 + arow) * DIM + k0 + ak);
        float4 wv = *(const float4*)(W + (size_t)(k0 + wrow) * DIM + c0 + wcol);
        __syncthreads();
        As[ak + 0][arow] = av.x; As[ak + 1][arow] = av.y;
        As[ak + 2][arow] = av.z; As[ak + 3][arow] = av.w;
        *(float4*)&Ws[wrow][wcol] = wv;
        __syncthreads();
#pragma unroll
        for (int kk = 0; kk < 16; ++kk) {
            float4 a = *(const float4*)&As[kk][ty * 4];
            float4 b = *(const float4*)&Ws[kk][tx * 4];
            float aa[4] = {a.x, a.y, a.z, a.w};
            float bb[4] = {b.x, b.y, b.z, b.w};
#pragma unroll
            for (int i = 0; i < 4; ++i)
#pragma unroll
                for (int j = 0; j < 4; ++j)
                    acc[i][j] = fmaf(aa[i], bb[j], acc[i][j]);
        }
    }
#pragma unroll
    for (int i = 0; i < 4; ++i) {
        float4 o;
        o.x = acc[i][0] + bias[c0 + tx * 4 + 0];
        o.y = acc[i][1] + bias[c0 + tx * 4 + 1];
        o.z = acc[i][2] + bias[c0 + tx * 4 + 2];
        o.w = acc[i][3] + bias[c0 + tx * 4 + 3];
        *(float4*)(out + (size_t)(r0 + ty * 4 + i) * DIM + c0 + tx * 4) = o;
    }
}

// ---------------- row squared norms ----------------
__global__ __launch_bounds__(64) void row_norm(const float* __restrict__ x,
                                               float* __restrict__ out) {
    const int row = blockIdx.x, lane = threadIdx.x;
    float4 v = *(const float4*)(x + (size_t)row * DIM + lane * 4);
    float s = v.x * v.x + v.y * v.y + v.z * v.z + v.w * v.w;
#pragma unroll
    for (int off = 32; off > 0; off >>= 1) s += __shfl_xor(s, off);
    if (lane == 0) out[row] = s;
}

// ---------------- MLP logits: relu(A@W1+b1)@W2 + b2 ----------------
__global__ __launch_bounds__(128) void mlp_logits(const float* __restrict__ A,
                                                  const float* __restrict__ W1,
                                                  const float* __restrict__ b1,
                                                  const float* __restrict__ W2,
                                                  const float* __restrict__ b2,
                                                  float* __restrict__ logits) {
    __shared__ float ar[DIM];
    __shared__ float red[2];
    const int t = threadIdx.x;
    const int row = blockIdx.x;
    *(float2*)&ar[t * 2] = *(const float2*)(A + (size_t)row * DIM + t * 2);
    __syncthreads();
    float h = b1[t];
#pragma unroll 8
    for (int kk = 0; kk < DIM; ++kk) h = fmaf(ar[kk], W1[kk * 128 + t], h);
    float val = fmaxf(h, 0.0f) * W2[t];
#pragma unroll
    for (int off = 32; off > 0; off >>= 1) val += __shfl_xor(val, off);
    if ((t & 63) == 0) red[t >> 6] = val;
    __syncthreads();
    if (t == 0) logits[row] = red[0] + red[1] + b2[0];
}

// ---------------- softmax over 8192 logits -> log(b + 1e-20) ----------------
__global__ __launch_bounds__(1024) void softmax_logb(const float* __restrict__ logits,
                                                     float* __restrict__ logb) {
    __shared__ float redm[16], reds[16];
    const int t = threadIdx.x;
    float l[8];
    float m = -INFINITY;
#pragma unroll
    for (int i = 0; i < 8; ++i) { l[i] = logits[i * 1024 + t]; m = fmaxf(m, l[i]); }
#pragma unroll
    for (int off = 32; off > 0; off >>= 1) m = fmaxf(m, __shfl_xor(m, off));
    if ((t & 63) == 0) redm[t >> 6] = m;
    __syncthreads();
    if (t < 64) {
        float v = (t < 16) ? redm[t] : -INFINITY;
#pragma unroll
        for (int off = 8; off > 0; off >>= 1) v = fmaxf(v, __shfl_xor(v, off));
        if (t == 0) redm[0] = v;
    }
    __syncthreads();
    m = redm[0];
    float s = 0.0f;
#pragma unroll
    for (int i = 0; i < 8; ++i) s += __expf(l[i] - m);
#pragma unroll
    for (int off = 32; off > 0; off >>= 1) s += __shfl_xor(s, off);
    if ((t & 63) == 0) reds[t >> 6] = s;
    __syncthreads();
    if (t < 64) {
        float v = (t < 16) ? reds[t] : 0.0f;
#pragma unroll
        for (int off = 8; off > 0; off >>= 1) v += __shfl_xor(v, off);
        if (t == 0) reds[0] = v;
    }
    __syncthreads();
    s = reds[0];
#pragma unroll
    for (int i = 0; i < 8; ++i)
        logb[i * 1024 + t] = logf(__expf(l[i] - m) / s + 1e-20f);
}

// ---------------- S[i][j] = 10*(qn_i + kn_j - 2*q_i.k_j) ----------------
// BM=BN=128, BK=16, 256 threads, 8x8 micro, wave remapped 8x8 to kill conflicts
__global__ __launch_bounds__(256) void dist_kernel(const float* __restrict__ q,
                                                   const float* __restrict__ k,
                                                   const float* __restrict__ qn,
                                                   const float* __restrict__ kn,
                                                   float* __restrict__ S) {
    __shared__ float Qs[16][132];
    __shared__ float Ks[16][132];
    const int t  = threadIdx.x;
    const int r0 = blockIdx.y * 128;
    const int c0 = blockIdx.x * 128;
    const int lrow = t >> 1;         // 0..127
    const int lk   = (t & 1) * 8;    // 0 or 8
    const int wv   = t >> 6;
    const int lane = t & 63;
    const int ty8 = (wv >> 1) * 8 + (lane >> 3);  // 0..15
    const int tx8 = (wv & 1) * 8 + (lane & 7);    // 0..15
    float acc[8][8] = {};
    for (int k0 = 0; k0 < DIM; k0 += 16) {
        float4 qa = *(const float4*)(q + (size_t)(r0 + lrow) * DIM + k0 + lk);
        float4 qb = *(const float4*)(q + (size_t)(r0 + lrow) * DIM + k0 + lk + 4);
        float4 ka = *(const float4*)(k + (size_t)(c0 + lrow) * DIM + k0 + lk);
        float4 kb = *(const float4*)(k + (size_t)(c0 + lrow) * DIM + k0 + lk + 4);
        __syncthreads();
        Qs[lk + 0][lrow] = qa.x; Qs[lk + 1][lrow] = qa.y;
        Qs[lk + 2][lrow] = qa.z; Qs[lk + 3][lrow] = qa.w;
        Qs[lk + 4][lrow] = qb.x; Qs[lk + 5][lrow] = qb.y;
        Qs[lk + 6][lrow] = qb.z; Qs[lk + 7][lrow] = qb.w;
        Ks[lk + 0][lrow] = ka.x; Ks[lk + 1][lrow] = ka.y;
        Ks[lk + 2][lrow] = ka.z; Ks[lk + 3][lrow] = ka.w;
        Ks[lk + 4][lrow] = kb.x; Ks[lk + 5][lrow] = kb.y;
        Ks[lk + 6][lrow] = kb.z; Ks[lk + 7][lrow] = kb.w;
        __syncthreads();
#pragma unroll
        for (int kk = 0; kk < 16; ++kk) {
            float4 a0 = *(const float4*)&Qs[kk][ty8 * 8];
            float4 a1 = *(const float4*)&Qs[kk][ty8 * 8 + 4];
            float4 b0 = *(const float4*)&Ks[kk][tx8 * 8];
            float4 b1 = *(const float4*)&Ks[kk][tx8 * 8 + 4];
            float aa[8] = {a0.x, a0.y, a0.z, a0.w, a1.x, a1.y, a1.z, a1.w};
            float bb[8] = {b0.x, b0.y, b0.z, b0.w, b1.x, b1.y, b1.z, b1.w};
#pragma unroll
            for (int i = 0; i < 8; ++i)
#pragma unroll
                for (int j = 0; j < 8; ++j)
                    acc[i][j] = fmaf(aa[i], bb[j], acc[i][j]);
        }
    }
    float knv[8];
#pragma unroll
    for (int j = 0; j < 8; ++j) knv[j] = kn[c0 + tx8 * 8 + j];
#pragma unroll
    for (int i = 0; i < 8; ++i) {
        const int row = r0 + ty8 * 8 + i;
        const float qni = qn[row];
        float* outp = S + (size_t)row * NR + c0 + tx8 * 8;
        float4 o0, o1;
        o0.x = (qni + knv[0] - 2.0f * acc[i][0]) * 10.0f;
        o0.y = (qni + knv[1] - 2.0f * acc[i][1]) * 10.0f;
        o0.z = (qni + knv[2] - 2.0f * acc[i][2]) * 10.0f;
        o0.w = (qni + knv[3] - 2.0f * acc[i][3]) * 10.0f;
        o1.x = (qni + knv[4] - 2.0f * acc[i][4]) * 10.0f;
        o1.y = (qni + knv[5] - 2.0f * acc[i][5]) * 10.0f;
        o1.z = (qni + knv[6] - 2.0f * acc[i][6]) * 10.0f;
        o1.w = (qni + knv[7] - 2.0f * acc[i][7]) * 10.0f;
        *(float4*)outp = o0;
        *(float4*)(outp + 4) = o1;
    }
}

// ---------------- f_i = logb_i - LSE_j(S_ij + g_j), one wave per row ----------------
__global__ __launch_bounds__(256) void row_lse(const float* __restrict__ S,
                                               const float* __restrict__ g,
                                               const float* __restrict__ logb,
                                               float* __restrict__ f) {
    const int wv = threadIdx.x >> 6;
    const int lane = threadIdx.x & 63;
    const int row = blockIdx.x * 4 + wv;
    const float4* Sr = (const float4*)(S + (size_t)row * NR);
    const float4* gr = (const float4*)g;
    float m = -INFINITY, s = 0.0f;
#pragma unroll 4
    for (int it = 0; it < NR / 256; ++it) {
        const int idx = it * 64 + lane;
        float4 sv = Sr[idx];
        float4 gv = gr[idx];
        lse_upd(m, s, sv.x + gv.x);
        lse_upd(m, s, sv.y + gv.y);
        lse_upd(m, s, sv.z + gv.z);
        lse_upd(m, s, sv.w + gv.w);
    }
#pragma unroll
    for (int off = 32; off > 0; off >>= 1) {
        float mo = __shfl_xor(m, off);
        float so = __shfl_xor(s, off);
        lse_comb(m, s, mo, so);
    }
    if (lane == 0) f[row] = logb[row] - (m + logf(s));
}

// ---------------- column-LSE partials over row chunks ----------------
__global__ __launch_bounds__(256) void col_lse_partial(const float* __restrict__ S,
                                                       const float* __restrict__ f,
                                                       float* __restrict__ pm,
                                                       float* __restrict__ ps) {
    __shared__ float fs[CHR];
    const int t = threadIdx.x;
    const int col = blockIdx.x * 256 + t;
    const int r0 = blockIdx.y * CHR;
    if (t < CHR) fs[t] = f[r0 + t];
    __syncthreads();
    float m = -INFINITY, s = 0.0f;
    const float* Sp = S + (size_t)r0 * NR + col;
#pragma unroll 8
    for (int i = 0; i < CHR; ++i) {
        lse_upd(m, s, Sp[(size_t)i * NR] + fs[i]);
    }
    pm[blockIdx.y * NR + col] = m;
    ps[blockIdx.y * NR + col] = s;
}

// ---------------- combine partials -> g ----------------
__global__ __launch_bounds__(256) void col_combine(const float* __restrict__ pm,
                                                   const float* __restrict__ ps,
                                                   float* __restrict__ g,
                                                   float log_a) {
    const int col = blockIdx.x * 256 + threadIdx.x;
    float m = -INFINITY, s = 0.0f;
#pragma unroll 8
    for (int ch = 0; ch < NCH; ++ch) {
        lse_comb(m, s, pm[ch * NR + col], ps[ch * NR + col]);
    }
    g[col] = log_a - (m + logf(s));
}

// ---------------- global sum of exp(f + S + g) ----------------
__global__ __launch_bounds__(256) void sum_pass(const float* __restrict__ S,
                                                const float* __restrict__ f,
                                                const float* __restrict__ g,
                                                float* __restrict__ sum) {
    const int wv = threadIdx.x >> 6, lane = threadIdx.x & 63;
    const int row = blockIdx.x * 4 + wv;
    const float fi = f[row];
    const float4* Sr = (const float4*)(S + (size_t)row * NR);
    const float4* gr = (const float4*)g;
    float acc = 0.0f;
#pragma unroll 4
    for (int it = 0; it < NR / 256; ++it) {
        const int idx = it * 64 + lane;
        float4 sv = Sr[idx];
        float4 gv = gr[idx];
        acc += __expf(fi + sv.x + gv.x);
        acc += __expf(fi + sv.y + gv.y);
        acc += __expf(fi + sv.z + gv.z);
        acc += __expf(fi + sv.w + gv.w);
    }
#pragma unroll
    for (int off = 32; off > 0; off >>= 1) acc += __shfl_xor(acc, off);
    if (lane == 0) atomicAdd(sum, acc);
}

// ---------------- T = exp(f + S + g) / (sum + 1e-8), in place ----------------
// note: no __restrict__ on S/out — they alias (in-place)
__global__ __launch_bounds__(256) void write_pass(const float* S,
                                                  const float* __restrict__ f,
                                                  const float* __restrict__ g,
                                                  const float* __restrict__ sum,
                                                  float* out) {
    const int wv = threadIdx.x >> 6, lane = threadIdx.x & 63;
    const int row = blockIdx.x * 4 + wv;
    const float inv = 1.0f / (*sum + 1e-8f);
    const float fi = f[row];
    const float4* Sr = (const float4*)(S + (size_t)row * NR);
    const float4* gr = (const float4*)g;
    float4* Or = (float4*)(out + (size_t)row * NR);
#pragma unroll 4
    for (int it = 0; it < NR / 256; ++it) {
        const int idx = it * 64 + lane;
        float4 sv = Sr[idx];
        float4 gv = gr[idx];
        float4 o;
        o.x = fmaxf(__expf(fi + sv.x + gv.x), 0.0f) * inv;
        o.y = fmaxf(__expf(fi + sv.y + gv.y), 0.0f) * inv;
        o.z = fmaxf(__expf(fi + sv.z + gv.z), 0.0f) * inv;
        o.w = fmaxf(__expf(fi + sv.w + gv.w), 0.0f) * inv;
        Or[idx] = o;
    }
}

extern "C" void kernel_launch(void* const* d_in, const int* in_sizes, int n_in,
                              void* d_out, int out_size, void* d_ws, size_t ws_size,
                              hipStream_t stream) {
    (void)in_sizes; (void)n_in; (void)out_size; (void)ws_size;
    const float* A  = (const float*)d_in[0];
    const float* Tk = (const float*)d_in[1];
    const float* Wq = (const float*)d_in[2];
    const float* bq = (const float*)d_in[3];
    const float* Wk = (const float*)d_in[4];
    const float* bk = (const float*)d_in[5];
    const float* W1 = (const float*)d_in[6];
    const float* b1 = (const float*)d_in[7];
    const float* W2 = (const float*)d_in[8];
    const float* b2 = (const float*)d_in[9];
    float* S  = (float*)d_out;           // 8192x8192 log_K lives in d_out
    float* ws = (float*)d_ws;
    float* q      = ws; ws += (size_t)NR * DIM;
    float* k      = ws; ws += (size_t)NR * DIM;
    float* qn     = ws; ws += NR;
    float* kn     = ws; ws += NR;
    float* logb   = ws; ws += NR;
    float* logits = ws; ws += NR;
    float* f      = ws; ws += NR;
    float* g      = ws; ws += NR;
    float* pm     = ws; ws += (size_t)NCH * NR;
    float* ps     = ws; ws += (size_t)NCH * NR;
    float* sum    = ws; ws += 1;

    const float log_a = logf(1.0f / 8192.0f + 1e-20f);

    init_zero<<<32, 256, 0, stream>>>(g, sum);
    gemm_qk<<<dim3(128, 4), 256, 0, stream>>>(A, Wq, bq, q);
    gemm_qk<<<dim3(128, 4), 256, 0, stream>>>(Tk, Wk, bk, k);
    row_norm<<<NR, 64, 0, stream>>>(q, qn);
    row_norm<<<NR, 64, 0, stream>>>(k, kn);
    mlp_logits<<<NR, 128, 0, stream>>>(A, W1, b1, W2, b2, logits);
    softmax_logb<<<1, 1024, 0, stream>>>(logits, logb);
    dist_kernel<<<dim3(64, 64), 256, 0, stream>>>(q, k, qn, kn, S);
    for (int it = 0; it < 50; ++it) {
        row_lse<<<NR / 4, 256, 0, stream>>>(S, g, logb, f);
        col_lse_partial<<<dim3(32, NCH), 256, 0, stream>>>(S, f, pm, ps);
        col_combine<<<32, 256, 0, stream>>>(pm, ps, g, log_a);
    }
    sum_pass<<<NR / 4, 256, 0, stream>>>(S, f, g, sum);
    write_pass<<<NR / 4, 256, 0, stream>>>(S, f, g, sum, S);
}